// Round 1
// 139.230 us; speedup vs baseline: 1.1607x; 1.1607x over previous
//
#include <hip/hip_runtime.h>

#define BATCH 32
#define H 512
#define W 512
#define PADR 4
#define WIN 9
#define SEG 16                      // output rows per block
#define COLS 4                      // output columns per thread
#define NSTEP (SEG + WIN - 1)       // 24 row-steps, fully unrolled
// final scalar = sum over pixels of ((1-cc1)+(1-cc2)) * 0.5 / (B*H*W)
#define SCALE (0.5f / 8388608.0f)

typedef float v4f __attribute__((ext_vector_type(4)));

// Horizontal 9-window sums for 4 consecutive output columns from the
// 12-pixel span Q[0..11] (pixel x0-4 .. x0+7), via one prefix chain:
// S[j] = sum_{k=j..j+8} Q[k].  11 adds + 3 subs per quantity.
#define HSUM(S, Q) do {                                   \
    float p = (Q)[0]; const float p0 = p;                 \
    p += (Q)[1]; const float p1 = p;                      \
    p += (Q)[2]; const float p2 = p;                      \
    p += (Q)[3]; p += (Q)[4]; p += (Q)[5];                \
    p += (Q)[6]; p += (Q)[7]; p += (Q)[8];                \
    (S)[0] = p;                                           \
    p += (Q)[9];  (S)[1] = p - p0;                        \
    p += (Q)[10]; (S)[2] = p - p1;                        \
    p += (Q)[11]; (S)[3] = p - p2;                        \
} while (0)

// Same, for a product quantity Qa*Qb — product folded into the chain as fma.
#define HSUM2(S, Qa, Qb) do {                             \
    float p = (Qa)[0] * (Qb)[0]; const float p0 = p;      \
    p = fmaf((Qa)[1], (Qb)[1], p); const float p1 = p;    \
    p = fmaf((Qa)[2], (Qb)[2], p); const float p2 = p;    \
    p = fmaf((Qa)[3], (Qb)[3], p);                        \
    p = fmaf((Qa)[4], (Qb)[4], p);                        \
    p = fmaf((Qa)[5], (Qb)[5], p);                        \
    p = fmaf((Qa)[6], (Qb)[6], p);                        \
    p = fmaf((Qa)[7], (Qb)[7], p);                        \
    p = fmaf((Qa)[8], (Qb)[8], p);                        \
    (S)[0] = p;                                           \
    p = fmaf((Qa)[9],  (Qb)[9],  p); (S)[1] = p - p0;     \
    p = fmaf((Qa)[10], (Qb)[10], p); (S)[2] = p - p1;     \
    p = fmaf((Qa)[11], (Qb)[11], p); (S)[3] = p - p2;     \
} while (0)

// (128, 1): allow the full 512-reg unified file — the 8x4x9 vertical ring
// (~288 floats) + double-buffered raw pixels (~72) is an intentional
// 1-wave/SIMD design; latency hiding comes from the unrolled pipeline.
__global__ __launch_bounds__(128, 1) void ncc_loss_kernel(
    const float* __restrict__ g1, const float* __restrict__ g2,
    const float* __restrict__ gf, float* __restrict__ out)
{
    const int t  = threadIdx.x;              // 0..127, covers all 512 columns
    const int x0 = t * COLS;                 // 0,4,...,508
    const int y0 = blockIdx.y * SEG;
    const int b  = blockIdx.z;
    const size_t base = (size_t)b * (size_t)(H * W);

    // Three aligned float4 spans cover pixels x0-4 .. x0+7.  Every load is
    // either fully in-bounds or fully OOB (middle span always valid), so
    // SRD bounds-check zeroing reproduces conv zero-padding exactly.
    const int voffM = x0 * 4;
    const int voffL = (x0 == 0) ? 0x7ffffff0 : (voffM - 16); // fully-OOB, no u32 wrap
    const int voffR = voffM + 16;            // x0=508 -> 2048 >= rec: OOB -> 0

    // Double-buffered raw-pixel registers: [parity][image][span pixel].
    float buf[2][3][12];

    // Issue the 9 float4 loads for row-step `step` into buf[parity].
    // Vertical padding: num_records=0 for OOB rows -> loads return 0.
    auto load_row = [&](int step, int par) {
        const int yr  = y0 - PADR + step;
        const int rec = ((unsigned)yr < (unsigned)H) ? (W * 4) : 0;
        const int yc  = yr < 0 ? 0 : (yr >= H ? H - 1 : yr);   // safe base
        const size_t roff = base + (size_t)yc * W;             // block-uniform
        const float* ptrs[3] = { g1 + roff, g2 + roff, gf + roff };
#pragma unroll
        for (int im = 0; im < 3; ++im) {
            __amdgpu_buffer_rsrc_t rs = __builtin_amdgcn_make_buffer_rsrc(
                (void*)ptrs[im], (short)0, rec, 0x00020000);
            const v4f L = __builtin_bit_cast(v4f,
                __builtin_amdgcn_raw_buffer_load_b128(rs, voffL, 0, 0));
            const v4f M = __builtin_bit_cast(v4f,
                __builtin_amdgcn_raw_buffer_load_b128(rs, voffM, 0, 0));
            const v4f R = __builtin_bit_cast(v4f,
                __builtin_amdgcn_raw_buffer_load_b128(rs, voffR, 0, 0));
            buf[par][im][0]  = L.x; buf[par][im][1]  = L.y;
            buf[par][im][2]  = L.z; buf[par][im][3]  = L.w;
            buf[par][im][4]  = M.x; buf[par][im][5]  = M.y;
            buf[par][im][6]  = M.z; buf[par][im][7]  = M.w;
            buf[par][im][8]  = R.x; buf[par][im][9]  = R.y;
            buf[par][im][10] = R.z; buf[par][im][11] = R.w;
        }
    };

    // 9-deep vertical ring of horizontal sums, per quantity per column.
    float rA [COLS][WIN], rC [COLS][WIN], rF [COLS][WIN], rAA[COLS][WIN],
          rCC[COLS][WIN], rFF[COLS][WIN], rAF[COLS][WIN], rCF[COLS][WIN];
#pragma unroll
    for (int j = 0; j < COLS; ++j)
#pragma unroll
        for (int i = 0; i < WIN; ++i) {
            rA[j][i]=0.f;  rC[j][i]=0.f;  rF[j][i]=0.f;  rAA[j][i]=0.f;
            rCC[j][i]=0.f; rFF[j][i]=0.f; rAF[j][i]=0.f; rCF[j][i]=0.f;
        }
    float vA[COLS], vC[COLS], vF[COLS], vAA[COLS],
          vCC[COLS], vFF[COLS], vAF[COLS], vCF[COLS];
#pragma unroll
    for (int j = 0; j < COLS; ++j) {
        vA[j]=0.f;  vC[j]=0.f;  vF[j]=0.f;  vAA[j]=0.f;
        vCC[j]=0.f; vFF[j]=0.f; vAF[j]=0.f; vCF[j]=0.f;
    }
    float lsum = 0.f;
    const float inv_n = 1.0f / 81.0f;

    load_row(0, 0);                          // prologue prefetch

    // Fully unrolled software pipeline: issue step s+1's 9 loads, then
    // consume step s's registers (compute covers the load latency).
#pragma unroll
    for (int s = 0; s < NSTEP; ++s) {
        if (s + 1 < NSTEP) load_row(s + 1, (s + 1) & 1);   // compile-time guard

        const float* A = buf[s & 1][0];
        const float* C = buf[s & 1][1];
        const float* F = buf[s & 1][2];

        // horizontal 9-sums for 4 columns of the 8 quantities (prefix chains)
        float sA [COLS], sC [COLS], sF [COLS], sAA[COLS],
              sCC[COLS], sFF[COLS], sAF[COLS], sCF[COLS];
        HSUM (sA,  A);
        HSUM (sC,  C);
        HSUM (sF,  F);
        HSUM2(sAA, A, A);
        HSUM2(sCC, C, C);
        HSUM2(sFF, F, F);
        HSUM2(sAF, A, F);
        HSUM2(sCF, C, F);

        const int ph = s % WIN;              // compile-time after unroll
#pragma unroll
        for (int j = 0; j < COLS; ++j) {
            vA [j] += sA [j] - rA [j][ph]; rA [j][ph] = sA [j];
            vC [j] += sC [j] - rC [j][ph]; rC [j][ph] = sC [j];
            vF [j] += sF [j] - rF [j][ph]; rF [j][ph] = sF [j];
            vAA[j] += sAA[j] - rAA[j][ph]; rAA[j][ph] = sAA[j];
            vCC[j] += sCC[j] - rCC[j][ph]; rCC[j][ph] = sCC[j];
            vFF[j] += sFF[j] - rFF[j][ph]; rFF[j][ph] = sFF[j];
            vAF[j] += sAF[j] - rAF[j][ph]; rAF[j][ph] = sAF[j];
            vCF[j] += sCF[j] - rCF[j][ph]; rCF[j][ph] = sCF[j];

            if (s >= WIN - 1) {              // emit output row y0+s-8, col x0+j
                const float u1 = vA[j] * inv_n;
                const float u2 = vC[j] * inv_n;
                const float uf = vF[j] * inv_n;
                const float cross1 = fmaf(-vA[j], uf, vAF[j]);
                const float var1   = fmaf(-vA[j], u1, vAA[j]);
                const float varf   = fmaf(-vF[j], uf, vFF[j]);
                const float cross2 = fmaf(-vC[j], uf, vCF[j]);
                const float var2   = fmaf(-vC[j], u2, vCC[j]);
                const float d1 = fmaf(var1, varf, 1e-5f);
                const float d2 = fmaf(var2, varf, 1e-5f);
                // cc1 + cc2 = (cross1^2*d2 + cross2^2*d1)/(d1*d2): single rcp
                const float inv = __builtin_amdgcn_rcpf(d1 * d2);
                float num = cross1 * cross1 * d2;
                num = fmaf(cross2 * cross2, d1, num);
                lsum += fmaf(-num, inv, 2.0f);   // (1-cc1)+(1-cc2)
            }
        }
    }

    // block reduction: wave shuffle -> LDS -> one atomic per block
#pragma unroll
    for (int offd = 32; offd > 0; offd >>= 1)
        lsum += __shfl_down(lsum, offd);
    __shared__ float wsum[2];
    const int lane = t & 63;
    const int wid  = t >> 6;
    if (lane == 0) wsum[wid] = lsum;
    __syncthreads();
    if (t == 0) atomicAdd(out, (wsum[0] + wsum[1]) * SCALE);
}

extern "C" void kernel_launch(void* const* d_in, const int* in_sizes, int n_in,
                              void* d_out, int out_size, void* d_ws, size_t ws_size,
                              hipStream_t stream) {
    const float* img1 = (const float*)d_in[0];
    const float* img2 = (const float*)d_in[1];
    const float* fimg = (const float*)d_in[2];
    float* out = (float*)d_out;

    hipMemsetAsync(out, 0, sizeof(float), stream);  // d_out re-poisoned each call

    dim3 grid(1, H / SEG, BATCH);        // (1, 32, 32) = 1024 blocks
    ncc_loss_kernel<<<grid, dim3(128), 0, stream>>>(img1, img2, fimg, out);
}

// Round 2
// 132.096 us; speedup vs baseline: 1.2234x; 1.0540x over previous
//
#include <hip/hip_runtime.h>

#define BATCH 32
#define H 512
#define W 512
#define PADR 4
#define WIN 9
#define SEG 16                      // output rows per block
#define COLS 4                      // output columns per thread
#define NT 128                      // threads per block (covers W=512)
#define NSTEP (SEG + WIN - 1)       // 24 row-steps, fully unrolled
// final scalar = sum over pixels of ((1-cc1)+(1-cc2)) * 0.5 / (B*H*W)
#define SCALE (0.5f / 8388608.0f)

typedef float v4f __attribute__((ext_vector_type(4)));

// Vertical-first NCC:
//  - per thread: raw-pixel ring (3 img x 9 rows x 4 cols) + 8 vertical
//    running box-sums V_q for its own 4 columns  -> ~165 persistent regs
//    (the old horizontal-sum ring was 288 -> AGPR overflow -> 1 wave/SIMD)
//  - horizontal 9-sum done per emit-step via LDS exchange of V_q rows
//    (double-buffered parity, ONE barrier per emit step)
//  - each thread loads only its own 4 columns: 3 b128/step (was 9)
__global__ __launch_bounds__(NT, 1) void ncc_loss_kernel(
    const float* __restrict__ g1, const float* __restrict__ g2,
    const float* __restrict__ gf, float* __restrict__ out)
{
    const int t  = threadIdx.x;              // 0..127
    const int x0 = t * COLS;                 // 0,4,...,508
    const int y0 = blockIdx.y * SEG;
    const int b  = blockIdx.z;
    const size_t base = (size_t)b * (size_t)(H * W);
    const int voff = x0 * 4;                 // always fully in-bounds horizontally

    // V exchange rows: [parity][quantity][4 guard | 512 cols | 4 guard]
    __shared__ __align__(16) float Vl[2][8][520];   // 33,280 B
    {   // zero the 2*8*8 = 128 guard entries, one per thread
        const int gp  = t & 7;               // 0..7
        const int q   = (t >> 3) & 7;        // 0..7
        const int p   = (t >> 6) & 1;        // 0..1
        const int idx = (gp < 4) ? gp : (512 + gp);
        Vl[p][q][idx] = 0.0f;                // ordered before reads by s=8 barrier
    }

    // Double-buffered prefetch: [parity][image], 4 pixels each.
    v4f buf[2][3];
    auto load_row = [&](int step, int par) {
        const int yr  = y0 - PADR + step;
        const int rec = ((unsigned)yr < (unsigned)H) ? (W * 4) : 0; // OOB row -> 0
        const int yc  = yr < 0 ? 0 : (yr >= H ? H - 1 : yr);        // safe base
        const size_t roff = base + (size_t)yc * W;                  // block-uniform
        __amdgpu_buffer_rsrc_t r1 = __builtin_amdgcn_make_buffer_rsrc(
            (void*)(g1 + roff), (short)0, rec, 0x00020000);
        __amdgpu_buffer_rsrc_t r2 = __builtin_amdgcn_make_buffer_rsrc(
            (void*)(g2 + roff), (short)0, rec, 0x00020000);
        __amdgpu_buffer_rsrc_t rf = __builtin_amdgcn_make_buffer_rsrc(
            (void*)(gf + roff), (short)0, rec, 0x00020000);
        buf[par][0] = __builtin_bit_cast(v4f,
            __builtin_amdgcn_raw_buffer_load_b128(r1, voff, 0, 0));
        buf[par][1] = __builtin_bit_cast(v4f,
            __builtin_amdgcn_raw_buffer_load_b128(r2, voff, 0, 0));
        buf[par][2] = __builtin_bit_cast(v4f,
            __builtin_amdgcn_raw_buffer_load_b128(rf, voff, 0, 0));
    };

    // Raw-pixel vertical ring (all indices compile-time after full unroll).
    float ring[3][WIN][COLS];
#pragma unroll
    for (int im = 0; im < 3; ++im)
#pragma unroll
        for (int i = 0; i < WIN; ++i)
#pragma unroll
            for (int c = 0; c < COLS; ++c) ring[im][i][c] = 0.f;

    // Vertical running box-sums: q = {A, C, F, AA, CC, FF, AF, CF}.
    float V[8][COLS];
#pragma unroll
    for (int q = 0; q < 8; ++q)
#pragma unroll
        for (int c = 0; c < COLS; ++c) V[q][c] = 0.f;

    float lsum = 0.f;
    const float inv_n = 1.0f / 81.0f;

    load_row(0, 0);                          // prologue prefetch

#pragma unroll
    for (int s = 0; s < NSTEP; ++s) {
        if (s + 1 < NSTEP) load_row(s + 1, (s + 1) & 1);   // compile-time guard

        const v4f A = buf[s & 1][0];
        const v4f C = buf[s & 1][1];
        const v4f F = buf[s & 1][2];
        const int ph = s % WIN;              // compile-time

        // vertical sliding update: V += new - old (products folded as fma)
#pragma unroll
        for (int c = 0; c < COLS; ++c) {
            const float n1 = A[c], n2 = C[c], nf = F[c];
            const float o1 = ring[0][ph][c], o2 = ring[1][ph][c],
                        of = ring[2][ph][c];
            V[0][c] += n1 - o1;
            V[1][c] += n2 - o2;
            V[2][c] += nf - of;
            V[3][c] = fmaf(n1, n1, fmaf(-o1, o1, V[3][c]));
            V[4][c] = fmaf(n2, n2, fmaf(-o2, o2, V[4][c]));
            V[5][c] = fmaf(nf, nf, fmaf(-of, of, V[5][c]));
            V[6][c] = fmaf(n1, nf, fmaf(-o1, of, V[6][c]));
            V[7][c] = fmaf(n2, nf, fmaf(-o2, of, V[7][c]));
            ring[0][ph][c] = n1; ring[1][ph][c] = n2; ring[2][ph][c] = nf;
        }

        if (s >= WIN - 1) {                  // emit output row y0 + s - 8
            const int par = s & 1;
            // publish this thread's 4 columns of each V_q
#pragma unroll
            for (int q = 0; q < 8; ++q) {
                v4f v; v.x = V[q][0]; v.y = V[q][1]; v.z = V[q][2]; v.w = V[q][3];
                *(v4f*)&Vl[par][q][4 + x0] = v;
            }
            __syncthreads();
            // horizontal 9-window sums for 4 cols from the 12-value span
            float S[8][COLS];
#pragma unroll
            for (int q = 0; q < 8; ++q) {
                const v4f w0 = *(const v4f*)&Vl[par][q][x0];      // cols x0-4..x0-1
                const v4f w1 = *(const v4f*)&Vl[par][q][x0 + 4];  // cols x0..x0+3
                const v4f w2 = *(const v4f*)&Vl[par][q][x0 + 8];  // cols x0+4..x0+7
                float p = w0.x;  const float a0 = p;
                p += w0.y;       const float a1 = p;
                p += w0.z;       const float a2 = p;
                p += w0.w;
                p += w1.x; p += w1.y; p += w1.z; p += w1.w;
                p += w2.x;       S[q][0] = p;
                p += w2.y;       S[q][1] = p - a0;
                p += w2.z;       S[q][2] = p - a1;
                p += w2.w;       S[q][3] = p - a2;
            }
            // NCC epilogue per column
#pragma unroll
            for (int c = 0; c < COLS; ++c) {
                const float sA = S[0][c], sC = S[1][c], sF = S[2][c];
                const float u1 = sA * inv_n;
                const float u2 = sC * inv_n;
                const float uf = sF * inv_n;
                const float cross1 = fmaf(-sA, uf, S[6][c]);
                const float var1   = fmaf(-sA, u1, S[3][c]);
                const float varf   = fmaf(-sF, uf, S[5][c]);
                const float cross2 = fmaf(-sC, uf, S[7][c]);
                const float var2   = fmaf(-sC, u2, S[4][c]);
                const float d1 = fmaf(var1, varf, 1e-5f);
                const float d2 = fmaf(var2, varf, 1e-5f);
                // cc1 + cc2 = (cross1^2*d2 + cross2^2*d1)/(d1*d2): single rcp
                const float inv = __builtin_amdgcn_rcpf(d1 * d2);
                float num = cross1 * cross1 * d2;
                num = fmaf(cross2 * cross2, d1, num);
                lsum += fmaf(-num, inv, 2.0f);   // (1-cc1)+(1-cc2)
            }
        }
    }

    // block reduction: wave shuffle -> LDS -> one atomic per block
#pragma unroll
    for (int offd = 32; offd > 0; offd >>= 1)
        lsum += __shfl_down(lsum, offd);
    __shared__ float wsum[2];
    const int lane = t & 63;
    const int wid  = t >> 6;
    if (lane == 0) wsum[wid] = lsum;
    __syncthreads();
    if (t == 0) atomicAdd(out, (wsum[0] + wsum[1]) * SCALE);
}

extern "C" void kernel_launch(void* const* d_in, const int* in_sizes, int n_in,
                              void* d_out, int out_size, void* d_ws, size_t ws_size,
                              hipStream_t stream) {
    const float* img1 = (const float*)d_in[0];
    const float* img2 = (const float*)d_in[1];
    const float* fimg = (const float*)d_in[2];
    float* out = (float*)d_out;

    hipMemsetAsync(out, 0, sizeof(float), stream);  // d_out re-poisoned each call

    dim3 grid(1, H / SEG, BATCH);        // (1, 32, 32) = 1024 blocks
    ncc_loss_kernel<<<grid, dim3(NT), 0, stream>>>(img1, img2, fimg, out);
}